// Round 11
// baseline (125.691 us; speedup 1.0000x reference)
//
#include <hip/hip_runtime.h>
#include <math.h>

// TensoIR physical rendering: N points x L lights -> 4 (N,3) outputs.
//
// R11: TRANSPOSED parallelization. One POINT per LANE (wave = 64 points,
// same light across lanes); 4 waves/block each take 128 of the 512 lights;
// block = 64 points, grid = N/64 = 512. Eliminates (vs R4, 52.7us):
//  - the 54-shuffle wave reduction        (~1/3 of measured VALU work)
//  - 64x-redundant per-point setup        (each lane sets up its own point)
//  - per-iter per-lane LDS table reads    (-> wave-uniform broadcast reads)
//  - half the VMEM issue (float4 register blocking, 4 lights per group)
// Final 4-way cross-wave reduction via small LDS buffer.
// Math body identical to R4 (2-dot algebra). No launch_bounds min-waves
// (R7 lesson). L!=512 falls back to the proven R4 kernel.

#define PI_F     3.14159265358979323846f
#define FOURPI_F (4.0f * PI_F)
#define MAXL     512

__device__ __forceinline__ float fast_rcp(float x)  { float r; asm("v_rcp_f32 %0, %1" : "=v"(r) : "v"(x)); return r; }
__device__ __forceinline__ float fast_rsq(float x)  { float r; asm("v_rsq_f32 %0, %1" : "=v"(r) : "v"(x)); return r; }
__device__ __forceinline__ float fast_exp2(float x) { float r; asm("v_exp_f32 %0, %1" : "=v"(r) : "v"(x)); return r; }
__device__ __forceinline__ float fast_log2(float x) { float r; asm("v_log_f32 %0, %1" : "=v"(r) : "v"(x)); return r; }

__device__ __forceinline__ float lin2srgb(float x) {
  float lin = 12.92f * x;
  float xe  = fmaxf(x, 1e-8f);
  float e   = 1.055f * fast_exp2(fast_log2(xe) * (1.0f / 2.4f)) - 0.055f;
  return (x <= 0.0031308f) ? lin : e;
}

__device__ __forceinline__ float clamp01(float x) { return fminf(fmaxf(x, 0.0f), 1.0f); }
__device__ __forceinline__ float clampe(float x)  { return fminf(fmaxf(x, 1e-6f), 1.0f); }

struct f3 { float x, y, z; };

// ---------------- R11 transposed kernel (L == 512) ----------------
__global__ void __launch_bounds__(256)
tensoir_render64(const float* __restrict__ viewdirs,
                 const float* __restrict__ albedo,
                 const float* __restrict__ roughness,
                 const float* __restrict__ fresnel,
                 const float* __restrict__ normal,
                 const float* __restrict__ light_dirs,
                 const float* __restrict__ law,
                 const float* __restrict__ env_rgbs,
                 const float* __restrict__ visibility,  // (N,512)
                 const float* __restrict__ indirect,    // (N,512,3)
                 float* __restrict__ out, int N) {
  constexpr int L = 512;
  __shared__ float4 s_ld[MAXL];    // normalized dir xyz, area weight
  __shared__ float4 s_env[MAXL];   // env rgb, pad
  __shared__ float  red[9][4][64]; // cross-wave partials

  const int tid  = threadIdx.x;
  const int lane = tid & 63;
  const int wid  = tid >> 6;

  // stage light table once per block (amortized over 64 points now)
  for (int l = tid; l < L; l += 256) {
    float lx = light_dirs[3 * l + 0];
    float ly = light_dirs[3 * l + 1];
    float lz = light_dirs[3 * l + 2];
    float inv = fast_rsq(fmaxf(lx * lx + ly * ly + lz * lz, 1e-12f));
    s_ld[l]  = make_float4(lx * inv, ly * inv, lz * inv, law[l]);
    s_env[l] = make_float4(env_rgbs[3 * l + 0], env_rgbs[3 * l + 1],
                           env_rgbs[3 * l + 2], 0.0f);
  }
  __syncthreads();

  int n = blockIdx.x * 64 + lane;
  if (n >= N) n = N - 1;  // duplicate lanes compute identical values

  // ---- per-lane (per-point) setup, done ONCE per point ----
  float vx = -viewdirs[3 * n + 0], vy = -viewdirs[3 * n + 1], vz = -viewdirs[3 * n + 2];
  float nx = normal[3 * n + 0], ny = normal[3 * n + 1], nz = normal[3 * n + 2];
  {
    float inv = fast_rsq(fmaxf(vx * vx + vy * vy + vz * vz, 1e-12f));
    vx *= inv; vy *= inv; vz *= inv;
  }
  {
    float inv = fast_rsq(fmaxf(nx * nx + ny * ny + nz * nz, 1e-12f));
    nx *= inv; ny *= inv; nz *= inv;
  }
  const float rough  = clamp01(roughness[n] * 0.9f + 0.09f);
  const float alpha  = rough * rough;
  const float alpha2 = alpha * alpha;
  const float a2m1   = alpha2 - 1.0f;
  const float kk     = (alpha + 2.0f * rough + 1.0f) * 0.125f;
  const float onemk  = 1.0f - kk;

  const float fr = fresnel[3 * n + 0], fg = fresnel[3 * n + 1], fb = fresnel[3 * n + 2];
  const float omfr = 1.0f - fr, omfg = 1.0f - fg, omfb = 1.0f - fb;
  const float ar = clamp01(albedo[3 * n + 0]) * (1.0f / PI_F);
  const float ag = clamp01(albedo[3 * n + 1]) * (1.0f / PI_F);
  const float ab = clamp01(albedo[3 * n + 2]) * (1.0f / PI_F);

  const float NoV0 = vx * nx + vy * ny + vz * nz;
  const float sgn  = (NoV0 >= 0.0f) ? 1.0f : -1.0f;
  const float aNoV = fabsf(NoV0);
  const float NoV  = clampe(aNoV);
  const float nom1 = NoV * onemk + kk;
  const float c1   = FOURPI_F * nom1;

  float s1r = 0, s1g = 0, s1b = 0;
  float s2r = 0, s2g = 0, s2b = 0;
  float s3r = 0, s3g = 0, s3b = 0;

  const float4* vis4 = (const float4*)(visibility + (size_t)n * L);
  const float4* ind4 = (const float4*)(indirect + (size_t)n * L * 3);

  const int l0 = wid * 128;   // this wave's 128-light segment

#define LIGHT_BODY(ld, ev, visv, ir_, ig_, ib_)                                 \
  do {                                                                          \
    const float cos0 = (ld).x * nx + (ld).y * ny + (ld).z * nz;                 \
    const float LoV  = (ld).x * vx + (ld).y * vy + (ld).z * vz;                 \
    const float cosine = fmaxf(cos0, 0.0f);                                     \
    const bool  mask   = cos0 > 1e-6f;                                          \
    const float w      = cosine * (ld).w;                                       \
    const float NoL0 = sgn * cos0;                                              \
    const float NoL  = clampe(NoL0);                                            \
    const float h2   = fmaf(2.0f, LoV, 2.0f);                                   \
    const float hinv = fast_rsq(fmaxf(h2, 1e-12f));                             \
    const float VoH  = clampe((1.0f + LoV) * hinv);                             \
    const float NoH  = clampe((NoL0 + aNoV) * hinv);                            \
    const float FMi = (-5.55473f * VoH - 6.98316f) * VoH;                       \
    const float p2  = fast_exp2(FMi);                                           \
    const float nom0 = fmaf(NoH * NoH, a2m1, 1.0f);                             \
    const float nom2 = fmaf(NoL, onemk, kk);                                    \
    const float nom  = fminf(fmaxf(c1 * (nom0 * nom0) * nom2, 1e-6f), FOURPI_F);\
    const float ss   = alpha2 * fast_rcp(nom);                                  \
    const float br = fmaf(fmaf(omfr, p2, fr), ss, ar);                          \
    const float bg = fmaf(fmaf(omfg, p2, fg), ss, ag);                          \
    const float bb = fmaf(fmaf(omfb, p2, fb), ss, ab);                          \
    const float vism = mask ? (visv) : 0.0f;                                    \
    const float irm  = mask ? (ir_) : 0.0f;                                     \
    const float igm  = mask ? (ig_) : 0.0f;                                     \
    const float ibm  = mask ? (ib_) : 0.0f;                                     \
    const float twr = br * w, twg = bg * w, twb = bb * w;                       \
    s1r = fmaf(twr, vism * (ev).x, s1r);                                        \
    s1g = fmaf(twg, vism * (ev).y, s1g);                                        \
    s1b = fmaf(twb, vism * (ev).z, s1b);                                        \
    s2r = fmaf(twr, (ev).x, s2r);                                               \
    s2g = fmaf(twg, (ev).y, s2g);                                               \
    s2b = fmaf(twb, (ev).z, s2b);                                               \
    s3r = fmaf(twr, irm, s3r);                                                  \
    s3g = fmaf(twg, igm, s3g);                                                  \
    s3b = fmaf(twb, ibm, s3b);                                                  \
  } while (0)

  // 32 groups of 4 lights; per group: 1 vis float4 + 3 ind float4 per lane,
  // 8 broadcast LDS reads (wave-uniform address).
  for (int g = 0; g < 32; ++g) {
    const int base = l0 + g * 4;
    const float4 va = vis4[base >> 2];
    const float4 i0 = ind4[(base >> 2) * 3 + 0];
    const float4 i1 = ind4[(base >> 2) * 3 + 1];
    const float4 i2 = ind4[(base >> 2) * 3 + 2];

    const float4 d0 = s_ld[base + 0], e0 = s_env[base + 0];
    const float4 d1 = s_ld[base + 1], e1 = s_env[base + 1];
    const float4 d2 = s_ld[base + 2], e2 = s_env[base + 2];
    const float4 d3 = s_ld[base + 3], e3 = s_env[base + 3];

    LIGHT_BODY(d0, e0, va.x, i0.x, i0.y, i0.z);
    LIGHT_BODY(d1, e1, va.y, i0.w, i1.x, i1.y);
    LIGHT_BODY(d2, e2, va.z, i1.z, i1.w, i2.x);
    LIGHT_BODY(d3, e3, va.w, i2.y, i2.z, i2.w);
  }
#undef LIGHT_BODY

  // cross-wave reduction: 4 partials per point
  red[0][wid][lane] = s1r; red[1][wid][lane] = s1g; red[2][wid][lane] = s1b;
  red[3][wid][lane] = s2r; red[4][wid][lane] = s2g; red[5][wid][lane] = s2b;
  red[6][wid][lane] = s3r; red[7][wid][lane] = s3g; red[8][wid][lane] = s3b;
  __syncthreads();

  if (wid == 0) {
    float t[9];
#pragma unroll
    for (int s = 0; s < 9; ++s)
      t[s] = red[s][0][lane] + red[s][1][lane] + red[s][2][lane] + red[s][3][lane];

    const size_t stride = (size_t)3 * N;
    float* o0 = out + 3 * (size_t)n;             // rgb
    float* o1 = o0 + stride;                     // wo_indir
    float* o2 = o1 + stride;                     // wo_vis
    float* o3 = o2 + stride;                     // indir
    f3 r0, r1, r2, r3;
    r0.x = lin2srgb(clamp01(t[0] + t[6]));
    r0.y = lin2srgb(clamp01(t[1] + t[7]));
    r0.z = lin2srgb(clamp01(t[2] + t[8]));
    r1.x = lin2srgb(t[0]); r1.y = lin2srgb(t[1]); r1.z = lin2srgb(t[2]);
    r2.x = lin2srgb(t[3]); r2.y = lin2srgb(t[4]); r2.z = lin2srgb(t[5]);
    r3.x = lin2srgb(t[6]); r3.y = lin2srgb(t[7]); r3.z = lin2srgb(t[8]);
    *(f3*)o0 = r0; *(f3*)o1 = r1; *(f3*)o2 = r2; *(f3*)o3 = r3;
  }
}

// ---------------- fallback: R4 kernel (runtime L) ----------------
__global__ void __launch_bounds__(256)
tensoir_render_generic(const float* __restrict__ viewdirs,
                       const float* __restrict__ albedo,
                       const float* __restrict__ roughness,
                       const float* __restrict__ fresnel,
                       const float* __restrict__ normal,
                       const float* __restrict__ light_dirs,
                       const float* __restrict__ law,
                       const float* __restrict__ env_rgbs,
                       const float* __restrict__ visibility,
                       const float* __restrict__ indirect,
                       float* __restrict__ out, int N, int L) {
  __shared__ float4 s_ld[MAXL];
  __shared__ float4 s_env[MAXL];

  const int tid = threadIdx.x;
  const int lane = tid & 63;
  int n = blockIdx.x * 4 + (tid >> 6);
  if (n >= N) n = N - 1;

  float vx = -viewdirs[3 * n + 0], vy = -viewdirs[3 * n + 1], vz = -viewdirs[3 * n + 2];
  float nx = normal[3 * n + 0], ny = normal[3 * n + 1], nz = normal[3 * n + 2];
  float rough0 = roughness[n];
  const float fr = fresnel[3 * n + 0], fg = fresnel[3 * n + 1], fb = fresnel[3 * n + 2];
  float ar0 = albedo[3 * n + 0], ag0 = albedo[3 * n + 1], ab0 = albedo[3 * n + 2];

  for (int l = tid; l < L && l < MAXL; l += 256) {
    float lx = light_dirs[3 * l + 0];
    float ly = light_dirs[3 * l + 1];
    float lz = light_dirs[3 * l + 2];
    float inv = fast_rsq(fmaxf(lx * lx + ly * ly + lz * lz, 1e-12f));
    s_ld[l]  = make_float4(lx * inv, ly * inv, lz * inv, law[l]);
    s_env[l] = make_float4(env_rgbs[3 * l + 0], env_rgbs[3 * l + 1],
                           env_rgbs[3 * l + 2], 0.0f);
  }
  __syncthreads();

  {
    float inv = fast_rsq(fmaxf(vx * vx + vy * vy + vz * vz, 1e-12f));
    vx *= inv; vy *= inv; vz *= inv;
  }
  {
    float inv = fast_rsq(fmaxf(nx * nx + ny * ny + nz * nz, 1e-12f));
    nx *= inv; ny *= inv; nz *= inv;
  }
  const float rough  = clamp01(rough0 * 0.9f + 0.09f);
  const float alpha  = rough * rough;
  const float alpha2 = alpha * alpha;
  const float a2m1   = alpha2 - 1.0f;
  const float kk     = (alpha + 2.0f * rough + 1.0f) * 0.125f;
  const float onemk  = 1.0f - kk;
  const float omfr = 1.0f - fr, omfg = 1.0f - fg, omfb = 1.0f - fb;
  const float ar = clamp01(ar0) * (1.0f / PI_F);
  const float ag = clamp01(ag0) * (1.0f / PI_F);
  const float ab = clamp01(ab0) * (1.0f / PI_F);
  const float NoV0 = vx * nx + vy * ny + vz * nz;
  const float sgn  = (NoV0 >= 0.0f) ? 1.0f : -1.0f;
  const float aNoV = fabsf(NoV0);
  const float NoV  = clampe(aNoV);
  const float nom1 = NoV * onemk + kk;
  const float c1   = FOURPI_F * nom1;

  float s1r = 0, s1g = 0, s1b = 0;
  float s2r = 0, s2g = 0, s2b = 0;
  float s3r = 0, s3g = 0, s3b = 0;

  const float* visrow = visibility + (size_t)n * L;
  const float* indrow = indirect + (size_t)n * L * 3;

  for (int i = lane; i < L; i += 64) {
    const float4 ld = s_ld[i];
    const float4 ev = s_env[i];
    const float visv = visrow[i];
    const float ir = indrow[3 * i + 0];
    const float ig = indrow[3 * i + 1];
    const float ib = indrow[3 * i + 2];
    const float cos0 = ld.x * nx + ld.y * ny + ld.z * nz;
    const float LoV  = ld.x * vx + ld.y * vy + ld.z * vz;
    const float cosine = fmaxf(cos0, 0.0f);
    const bool  mask   = cos0 > 1e-6f;
    const float w      = cosine * ld.w;
    const float NoL0 = sgn * cos0;
    const float NoL  = clampe(NoL0);
    const float h2   = fmaf(2.0f, LoV, 2.0f);
    const float hinv = fast_rsq(fmaxf(h2, 1e-12f));
    const float VoH  = clampe((1.0f + LoV) * hinv);
    const float NoH  = clampe((NoL0 + aNoV) * hinv);
    const float FMi = (-5.55473f * VoH - 6.98316f) * VoH;
    const float p2  = fast_exp2(FMi);
    const float nom0 = fmaf(NoH * NoH, a2m1, 1.0f);
    const float nom2 = fmaf(NoL, onemk, kk);
    const float nom  = fminf(fmaxf(c1 * (nom0 * nom0) * nom2, 1e-6f), FOURPI_F);
    const float ss   = alpha2 * fast_rcp(nom);
    const float br = fmaf(fmaf(omfr, p2, fr), ss, ar);
    const float bg = fmaf(fmaf(omfg, p2, fg), ss, ag);
    const float bb = fmaf(fmaf(omfb, p2, fb), ss, ab);
    const float vism = mask ? visv : 0.0f;
    const float irm  = mask ? ir : 0.0f;
    const float igm  = mask ? ig : 0.0f;
    const float ibm  = mask ? ib : 0.0f;
    const float twr = br * w, twg = bg * w, twb = bb * w;
    s1r = fmaf(twr, vism * ev.x, s1r);
    s1g = fmaf(twg, vism * ev.y, s1g);
    s1b = fmaf(twb, vism * ev.z, s1b);
    s2r = fmaf(twr, ev.x, s2r);
    s2g = fmaf(twg, ev.y, s2g);
    s2b = fmaf(twb, ev.z, s2b);
    s3r = fmaf(twr, irm, s3r);
    s3g = fmaf(twg, igm, s3g);
    s3b = fmaf(twb, ibm, s3b);
  }

#define WAVE_RED(v)                 \
  do {                              \
    v += __shfl_xor(v, 32);         \
    v += __shfl_xor(v, 16);         \
    v += __shfl_xor(v, 8);          \
    v += __shfl_xor(v, 4);          \
    v += __shfl_xor(v, 2);          \
    v += __shfl_xor(v, 1);          \
  } while (0)
  WAVE_RED(s1r); WAVE_RED(s1g); WAVE_RED(s1b);
  WAVE_RED(s2r); WAVE_RED(s2g); WAVE_RED(s2b);
  WAVE_RED(s3r); WAVE_RED(s3g); WAVE_RED(s3b);
#undef WAVE_RED

  if (lane == 0) {
    const size_t stride = (size_t)3 * N;
    float* o0 = out + 3 * (size_t)n;
    float* o1 = o0 + stride;
    float* o2 = o1 + stride;
    float* o3 = o2 + stride;
    o0[0] = lin2srgb(clamp01(s1r + s3r));
    o0[1] = lin2srgb(clamp01(s1g + s3g));
    o0[2] = lin2srgb(clamp01(s1b + s3b));
    o1[0] = lin2srgb(s1r); o1[1] = lin2srgb(s1g); o1[2] = lin2srgb(s1b);
    o2[0] = lin2srgb(s2r); o2[1] = lin2srgb(s2g); o2[2] = lin2srgb(s2b);
    o3[0] = lin2srgb(s3r); o3[1] = lin2srgb(s3g); o3[2] = lin2srgb(s3b);
  }
}

extern "C" void kernel_launch(void* const* d_in, const int* in_sizes, int n_in,
                              void* d_out, int out_size, void* d_ws, size_t ws_size,
                              hipStream_t stream) {
  const float* viewdirs   = (const float*)d_in[0];
  const float* albedo     = (const float*)d_in[1];
  const float* roughness  = (const float*)d_in[2];
  const float* fresnel    = (const float*)d_in[3];
  const float* normal     = (const float*)d_in[4];
  const float* light_dirs = (const float*)d_in[5];
  const float* law        = (const float*)d_in[6];
  const float* env_rgbs   = (const float*)d_in[7];
  const float* visibility = (const float*)d_in[8];
  const float* indirect   = (const float*)d_in[9];
  float* out = (float*)d_out;

  const int N = in_sizes[0] / 3;
  const int L = in_sizes[6];   // light_area_weight is (L,)

  dim3 block(256);

  if (L == 512) {
    const int blocks = (N + 63) / 64;   // 512 for N=32768
    hipLaunchKernelGGL(tensoir_render64, dim3(blocks), block, 0, stream,
                       viewdirs, albedo, roughness, fresnel, normal,
                       light_dirs, law, env_rgbs, visibility, indirect,
                       out, N);
  } else {
    const int blocks = (N + 3) / 4;
    hipLaunchKernelGGL(tensoir_render_generic, dim3(blocks), block, 0, stream,
                       viewdirs, albedo, roughness, fresnel, normal,
                       light_dirs, law, env_rgbs, visibility, indirect,
                       out, N, L);
  }
}